// Round 6
// baseline (681.164 us; speedup 1.0000x reference)
//
#include <hip/hip_runtime.h>
#include <hip/hip_bf16.h>
#include <stdint.h>

#define N_TOK 4096   // B*S
#define KF    8192   // IN_F
#define NF    8192   // OUT_F

#define BM 256
#define BN 256
#define NT (KF / 64)    // 128 K-tiles of 64

typedef __attribute__((ext_vector_type(8))) short short8;
typedef __attribute__((ext_vector_type(4))) float f32x4;

#define GLOBAL_P(p) ((const __attribute__((address_space(1))) void*)(p))
#define LDS_P(p)    ((__attribute__((address_space(3))) void*)(p))

// ---------- pass 1: int8-quantize activations, store as bf16 (exact) ----------
__global__ void quant_x(const float* __restrict__ x, const float* __restrict__ scale_p,
                        uint16_t* __restrict__ a) {
    const float s = *scale_p;
    const int n8 = N_TOK * KF / 8;
    const int stride = gridDim.x * blockDim.x;
    for (int i = blockIdx.x * blockDim.x + threadIdx.x; i < n8; i += stride) {
        const float4* xp = (const float4*)(x + (size_t)i * 8);
        float4 v0 = xp[0], v1 = xp[1];
        float q[8] = {v0.x, v0.y, v0.z, v0.w, v1.x, v1.y, v1.z, v1.w};
        union { uint16_t u16[8]; short8 v; } o;
        #pragma unroll
        for (int j = 0; j < 8; ++j) {
            float t = rintf(q[j] / s);
            t = fminf(fmaxf(t, -128.f), 127.f);
            union { float f; uint32_t u; } cv; cv.f = t;
            o.u16[j] = (uint16_t)(cv.u >> 16);
        }
        *(short8*)(a + (size_t)i * 8) = o.v;
    }
}

// ---------- pass 2: unpack nibbles + signs -> bf16 weights (exact powers of 2) ----------
__global__ void dequant_w(const int* __restrict__ packed, const int* __restrict__ signs,
                          const int* __restrict__ minexp_p, uint16_t* __restrict__ w) {
    const int me = *minexp_p;
    const int ebase = (me + 127) << 7;
    const int n4 = NF * (KF / 2) / 4;
    const int stride = gridDim.x * blockDim.x;
    for (int i = blockIdx.x * blockDim.x + threadIdx.x; i < n4; i += stride) {
        int4 p  = ((const int4*)packed)[i];
        int4 s0 = ((const int4*)signs)[(size_t)i * 2];
        int4 s1 = ((const int4*)signs)[(size_t)i * 2 + 1];
        int pw[4] = {p.x, p.y, p.z, p.w};
        int sg[8] = {s0.x, s0.y, s0.z, s0.w, s1.x, s1.y, s1.z, s1.w};
        union { uint16_t u16[8]; short8 v; } o;
        #pragma unroll
        for (int j = 0; j < 4; ++j) {
            int lo = pw[j] & 0xF, hi = (pw[j] >> 4) & 0xF;
            o.u16[2 * j]     = (uint16_t)((ebase + (lo << 7)) | (sg[2 * j]     < 0 ? 0x8000 : 0));
            o.u16[2 * j + 1] = (uint16_t)((ebase + (hi << 7)) | (sg[2 * j + 1] < 0 ? 0x8000 : 0));
        }
        *(short8*)(w + (size_t)i * 8) = o.v;
    }
}

// ---------- pass 3: 256x256-tile m201-style 4-phase bf16 GEMM ----------
// out[M,N] = A[M,K] * W[N,K]^T * s + bias
// m201 discipline: per phase {ds_read CURRENT frags; STAGE; barrier; lgkmcnt(0)+sched0;
// setprio1; 16 MFMA; setprio0; [vmcnt(8)]; barrier}. Reads drain DURING barrier wait;
// staging loads stay in flight across phases under counted vmcnt (never 0 in main loop).
#define BARRIER()  __builtin_amdgcn_s_barrier()
#define SCHED0()   __builtin_amdgcn_sched_barrier(0)
#define LGKM0()    do { asm volatile("s_waitcnt lgkmcnt(0)"); SCHED0(); } while (0)
#define WAITVM8()  do { asm volatile("s_waitcnt vmcnt(8)"); SCHED0(); } while (0)
#define WAITVM4()  do { asm volatile("s_waitcnt vmcnt(4)"); SCHED0(); } while (0)
#define WAITVM0()  do { asm volatile("s_waitcnt vmcnt(0)"); SCHED0(); } while (0)
#define SP1 __builtin_amdgcn_s_setprio(1)
#define SP0 __builtin_amdgcn_s_setprio(0)

__global__ __launch_bounds__(512, 2) void gemm_bt(
        const uint16_t* __restrict__ A, const uint16_t* __restrict__ W,
        const float* __restrict__ bias, const float* __restrict__ scale_p,
        float* __restrict__ out) {
    // 4-slot K-half ring per operand: slot = 256 rows x 32 cols bf16 = 16 KiB
    __shared__ uint16_t ldsA[4 * 256 * 32];   // 64 KiB
    __shared__ uint16_t ldsB[4 * 256 * 32];   // 64 KiB

    const int tid  = threadIdx.x;
    const int wid  = tid >> 6, lane = tid & 63;
    const int wr = wid >> 2, wc = wid & 3;         // 2x4 wave grid; wave tile 128x64
    const int rlane = lane & 15, kgrp = lane >> 4;

    // XCD-region mapping (round-3, verified: FETCH 2.1GB -> 453MB)
    const int bid = blockIdx.x;        // 0..511
    const int xcd = bid & 7;
    const int i_l = bid >> 3;          // 0..63
    const int gen = i_l >> 5;          // 0,1
    const int il  = i_l & 31;          // 0..31
    const int by  = gen * 8 + (il >> 2);   // 0..15
    const int bx  = xcd * 4 + (il & 3);    // 0..31
    const int rowA0 = by * BM;
    const int colB0 = bx * BN;

    // staging: LDS physical o = (q*512+tid)*16 linear; global source pre-swizzled (st_16x32)
    const int o0 = tid * 16, o1 = (512 + tid) * 16;
    const int l0 = o0 ^ (((o0 >> 9) & 1) << 5);
    const int l1 = o1 ^ (((o1 >> 9) & 1) << 5);
    const char* gA0 = (const char*)A + ((size_t)(rowA0 + (l0 >> 6)) * KF) * 2 + (l0 & 63);
    const char* gA1 = (const char*)A + ((size_t)(rowA0 + (l1 >> 6)) * KF) * 2 + (l1 & 63);
    const char* gB0 = (const char*)W + ((size_t)(colB0 + (l0 >> 6)) * KF) * 2 + (l0 & 63);
    const char* gB1 = (const char*)W + ((size_t)(colB0 + (l1 >> 6)) * KF) * 2 + (l1 & 63);
    const int ldst0 = wid * 1024;
    const int ldst1 = 8192 + wid * 1024;

    // fragment read offsets (swizzled), compile-time indexed after unroll
    int aoff[8], boff[4];
    #pragma unroll
    for (int i = 0; i < 8; ++i) {
        int row = wr * 128 + i * 16 + rlane;
        int o = row * 64 + kgrp * 16;
        aoff[i] = o ^ (((o >> 9) & 1) << 5);
    }
    #pragma unroll
    for (int n = 0; n < 4; ++n) {
        int row = wc * 64 + n * 16 + rlane;
        int o = row * 64 + kgrp * 16;
        boff[n] = o ^ (((o >> 9) & 1) << 5);
    }

#define STAGE_A(j) do { \
    char* b_ = (char*)ldsA + ((j) & 3) * 16384; \
    __builtin_amdgcn_global_load_lds(GLOBAL_P(gA0 + (size_t)(j) * 64), LDS_P(b_ + ldst0), 16, 0, 0); \
    __builtin_amdgcn_global_load_lds(GLOBAL_P(gA1 + (size_t)(j) * 64), LDS_P(b_ + ldst1), 16, 0, 0); \
} while (0)
#define STAGE_B(j) do { \
    char* b_ = (char*)ldsB + ((j) & 3) * 16384; \
    __builtin_amdgcn_global_load_lds(GLOBAL_P(gB0 + (size_t)(j) * 64), LDS_P(b_ + ldst0), 16, 0, 0); \
    __builtin_amdgcn_global_load_lds(GLOBAL_P(gB1 + (size_t)(j) * 64), LDS_P(b_ + ldst1), 16, 0, 0); \
} while (0)
#define LDA4(H, SLOT) do { \
    const char* p_ = (const char*)ldsA + (SLOT) * 16384; \
    _Pragma("unroll") for (int i_ = 0; i_ < 4; ++i_) \
        afr[i_] = *(const short8*)(p_ + aoff[(H) * 4 + i_]); \
} while (0)
#define LDB4(SLOT) do { \
    const char* p_ = (const char*)ldsB + (SLOT) * 16384; \
    _Pragma("unroll") for (int i_ = 0; i_ < 4; ++i_) \
        bfr[i_] = *(const short8*)(p_ + boff[i_]); \
} while (0)
#define MFMA16(H) do { \
    SP1; \
    _Pragma("unroll") for (int mm_ = 0; mm_ < 4; ++mm_) \
        _Pragma("unroll") for (int nn_ = 0; nn_ < 4; ++nn_) \
            acc[(H) * 4 + mm_][nn_] = __builtin_amdgcn_mfma_f32_16x16x32_bf16( \
                afr[mm_], bfr[nn_], acc[(H) * 4 + mm_][nn_], 0, 0, 0); \
    SP0; \
} while (0)

    f32x4 acc[8][4] = {};
    short8 afr[4], bfr[4];

    // ---- prologue: stage Kh0..Kh2 (slots 0,1,2); Kh0 ready ----
    STAGE_A(0); STAGE_B(0);
    STAGE_A(1); STAGE_B(1);
    STAGE_A(2); STAGE_B(2);
    WAITVM8();                 // Kh0 A,B landed; Kh1,Kh2 in flight
    BARRIER();

    // ---- main loop: t = 0..125 uniform ----
    for (int t = 0; t < 126; ++t) {
        const int j0 = 2 * t;
        const int s0 = j0 & 3, s1 = (j0 + 1) & 3;
        // ph0
        LDA4(0, s0); LDB4(s0); STAGE_A(j0 + 3);
        BARRIER(); LGKM0();
        MFMA16(0);
        BARRIER();
        // ph1
        LDA4(1, s0); STAGE_B(j0 + 3);
        BARRIER(); LGKM0();
        MFMA16(1);
        WAITVM8();             // publish Kh(j0+1): <=8 outstanding = last 4 stages
        BARRIER();
        // ph2
        LDA4(0, s1); LDB4(s1); STAGE_A(j0 + 4);
        BARRIER(); LGKM0();
        MFMA16(0);
        BARRIER();
        // ph3
        LDA4(1, s1); STAGE_B(j0 + 4);
        BARRIER(); LGKM0();
        MFMA16(1);
        WAITVM8();             // publish Kh(j0+2)
        BARRIER();
    }

    // ---- t = 126 (j0 = 252, slots 0/1): stages Kh255 only ----
    LDA4(0, 0); LDB4(0); STAGE_A(255);
    BARRIER(); LGKM0();
    MFMA16(0);
    BARRIER();
    LDA4(1, 0); STAGE_B(255);
    BARRIER(); LGKM0();
    MFMA16(1);
    WAITVM8();                 // publish Kh253
    BARRIER();
    LDA4(0, 1); LDB4(1);
    BARRIER(); LGKM0();
    MFMA16(0);
    BARRIER();
    LDA4(1, 1);
    BARRIER(); LGKM0();
    MFMA16(1);
    WAITVM4();                 // publish Kh254 (only A255,B255 may remain)
    BARRIER();

    // ---- t = 127 (slots 2/3): no stages ----
    LDA4(0, 2); LDB4(2);
    BARRIER(); LGKM0();
    MFMA16(0);
    BARRIER();
    LDA4(1, 2);
    BARRIER(); LGKM0();
    MFMA16(1);
    WAITVM0();                 // publish Kh255
    BARRIER();
    LDA4(0, 3); LDB4(3);
    BARRIER(); LGKM0();
    MFMA16(0);
    BARRIER();
    LDA4(1, 3);
    LGKM0();
    MFMA16(1);

    // ---- epilogue: C/D layout col = lane&15, row = (lane>>4)*4 + r ----
    const float s = *scale_p;
    const int colbase = colB0 + wc * 64 + rlane;
    const int rowbase = rowA0 + wr * 128 + kgrp * 4;
    #pragma unroll
    for (int n = 0; n < 4; ++n) {
        const float bv = bias[colbase + n * 16];
        #pragma unroll
        for (int mf = 0; mf < 8; ++mf) {
            #pragma unroll
            for (int r = 0; r < 4; ++r)
                out[(size_t)(rowbase + mf * 16 + r) * NF + colbase + n * 16] = acc[mf][n][r] * s + bv;
        }
    }
#undef STAGE_A
#undef STAGE_B
#undef LDA4
#undef LDB4
#undef MFMA16
}

extern "C" void kernel_launch(void* const* d_in, const int* in_sizes, int n_in,
                              void* d_out, int out_size, void* d_ws, size_t ws_size,
                              hipStream_t stream) {
    const float* x      = (const float*)d_in[0];
    const int*   packed = (const int*)d_in[1];
    const int*   signs  = (const int*)d_in[2];
    const float* bias   = (const float*)d_in[3];
    const float* scale  = (const float*)d_in[4];
    const int*   minexp = (const int*)d_in[5];
    float* out = (float*)d_out;

    uint16_t* A = (uint16_t*)d_ws;                                       // 64 MiB
    uint16_t* W = (uint16_t*)((char*)d_ws + (size_t)N_TOK * KF * 2);     // 128 MiB

    quant_x<<<2048, 256, 0, stream>>>(x, scale, A);
    dequant_w<<<2048, 256, 0, stream>>>(packed, signs, minexp, W);
    gemm_bt<<<(N_TOK / BM) * (NF / BN), 512, 0, stream>>>(A, W, bias, scale, out);
}

// Round 8
// 604.165 us; speedup vs baseline: 1.1274x; 1.1274x over previous
//
#include <hip/hip_runtime.h>
#include <hip/hip_bf16.h>
#include <stdint.h>

#define N_TOK 4096   // B*S
#define KF    8192   // IN_F
#define NF    8192   // OUT_F

#define BM 256
#define BN 256

typedef __attribute__((ext_vector_type(8))) short short8;
typedef __attribute__((ext_vector_type(4))) float f32x4;

#define GLOBAL_P(p) ((const __attribute__((address_space(1))) void*)(p))
#define LDS_P(p)    ((__attribute__((address_space(3))) void*)(p))

// ---------- pass 1: int8-quantize activations, store as bf16 (exact) ----------
__global__ void quant_x(const float* __restrict__ x, const float* __restrict__ scale_p,
                        uint16_t* __restrict__ a) {
    const float s = *scale_p;
    const int n8 = N_TOK * KF / 8;
    const int stride = gridDim.x * blockDim.x;
    for (int i = blockIdx.x * blockDim.x + threadIdx.x; i < n8; i += stride) {
        const float4* xp = (const float4*)(x + (size_t)i * 8);
        float4 v0 = xp[0], v1 = xp[1];
        float q[8] = {v0.x, v0.y, v0.z, v0.w, v1.x, v1.y, v1.z, v1.w};
        union { uint16_t u16[8]; short8 v; } o;
        #pragma unroll
        for (int j = 0; j < 8; ++j) {
            float t = rintf(q[j] / s);
            t = fminf(fmaxf(t, -128.f), 127.f);
            union { float f; uint32_t u; } cv; cv.f = t;
            o.u16[j] = (uint16_t)(cv.u >> 16);
        }
        *(short8*)(a + (size_t)i * 8) = o.v;
    }
}

// ---------- pass 2: unpack nibbles + signs -> bf16 weights (exact powers of 2) ----------
__global__ void dequant_w(const int* __restrict__ packed, const int* __restrict__ signs,
                          const int* __restrict__ minexp_p, uint16_t* __restrict__ w) {
    const int me = *minexp_p;
    const int ebase = (me + 127) << 7;
    const int n4 = NF * (KF / 2) / 4;
    const int stride = gridDim.x * blockDim.x;
    for (int i = blockIdx.x * blockDim.x + threadIdx.x; i < n4; i += stride) {
        int4 p  = ((const int4*)packed)[i];
        int4 s0 = ((const int4*)signs)[(size_t)i * 2];
        int4 s1 = ((const int4*)signs)[(size_t)i * 2 + 1];
        int pw[4] = {p.x, p.y, p.z, p.w};
        int sg[8] = {s0.x, s0.y, s0.z, s0.w, s1.x, s1.y, s1.z, s1.w};
        union { uint16_t u16[8]; short8 v; } o;
        #pragma unroll
        for (int j = 0; j < 4; ++j) {
            int lo = pw[j] & 0xF, hi = (pw[j] >> 4) & 0xF;
            o.u16[2 * j]     = (uint16_t)((ebase + (lo << 7)) | (sg[2 * j]     < 0 ? 0x8000 : 0));
            o.u16[2 * j + 1] = (uint16_t)((ebase + (hi << 7)) | (sg[2 * j + 1] < 0 ? 0x8000 : 0));
        }
        *(short8*)(w + (size_t)i * 8) = o.v;
    }
}

// ---------- pass 3: 256x256-tile bf16 GEMM, 1 barrier per K-half window ----------
// out[M,N] = A[M,K] * W[N,K]^T * s + bias
// Window j (cur = Kh j): {BAR; LD curA-h1; STAGE_A(j+3); 16 MFMA(h0);
//   LD nextA-h0 + nextB (slot j+1); STAGE_B(j+3); 16 MFMA(h1); VM4}.
// Publication: VM4 at END of window j proves Kh(j+2) stages retired in every wave
// BEFORE the barrier that opens window j+1 -> reads after that barrier are safe.
// (Round-7 bug: VM placed after the barrier, reads in same window = cross-wave race.)
#define BARRIER()  __builtin_amdgcn_s_barrier()
#define SCHED0()   __builtin_amdgcn_sched_barrier(0)
#define WAITVM4()  do { asm volatile("s_waitcnt vmcnt(4)"); SCHED0(); } while (0)
#define WAITVM0()  do { asm volatile("s_waitcnt vmcnt(0)"); SCHED0(); } while (0)
#define SP1 __builtin_amdgcn_s_setprio(1)
#define SP0 __builtin_amdgcn_s_setprio(0)

__global__ __launch_bounds__(512, 2) void gemm_bt(
        const uint16_t* __restrict__ A, const uint16_t* __restrict__ W,
        const float* __restrict__ bias, const float* __restrict__ scale_p,
        float* __restrict__ out) {
    // 4-slot K-half ring per operand: slot = 256 rows x 32 cols bf16 = 16 KiB
    __shared__ uint16_t ldsA[4 * 256 * 32];   // 64 KiB
    __shared__ uint16_t ldsB[4 * 256 * 32];   // 64 KiB

    const int tid  = threadIdx.x;
    const int wid  = tid >> 6, lane = tid & 63;
    const int wr = wid >> 2, wc = wid & 3;         // 2x4 wave grid; wave tile 128x64
    const int rlane = lane & 15, kgrp = lane >> 4;

    // XCD-region mapping (round-3, verified: FETCH 2.1GB -> 453MB)
    const int bid = blockIdx.x;        // 0..511
    const int xcd = bid & 7;
    const int i_l = bid >> 3;          // 0..63
    const int gen = i_l >> 5;          // 0,1
    const int il  = i_l & 31;          // 0..31
    const int by  = gen * 8 + (il >> 2);   // 0..15
    const int bx  = xcd * 4 + (il & 3);    // 0..31
    const int rowA0 = by * BM;
    const int colB0 = bx * BN;

    // staging: LDS physical o = (q*512+tid)*16 linear; global source pre-swizzled (st_16x32)
    const int o0 = tid * 16, o1 = (512 + tid) * 16;
    const int l0 = o0 ^ (((o0 >> 9) & 1) << 5);
    const int l1 = o1 ^ (((o1 >> 9) & 1) << 5);
    const char* gA0 = (const char*)A + ((size_t)(rowA0 + (l0 >> 6)) * KF) * 2 + (l0 & 63);
    const char* gA1 = (const char*)A + ((size_t)(rowA0 + (l1 >> 6)) * KF) * 2 + (l1 & 63);
    const char* gB0 = (const char*)W + ((size_t)(colB0 + (l0 >> 6)) * KF) * 2 + (l0 & 63);
    const char* gB1 = (const char*)W + ((size_t)(colB0 + (l1 >> 6)) * KF) * 2 + (l1 & 63);
    const int ldst0 = wid * 1024;
    const int ldst1 = 8192 + wid * 1024;

    // fragment read offsets (swizzled), compile-time indexed after unroll
    int aoff[8], boff[4];
    #pragma unroll
    for (int i = 0; i < 8; ++i) {
        int row = wr * 128 + i * 16 + rlane;
        int o = row * 64 + kgrp * 16;
        aoff[i] = o ^ (((o >> 9) & 1) << 5);
    }
    #pragma unroll
    for (int n = 0; n < 4; ++n) {
        int row = wc * 64 + n * 16 + rlane;
        int o = row * 64 + kgrp * 16;
        boff[n] = o ^ (((o >> 9) & 1) << 5);
    }

#define STAGE_A(j) do { \
    char* b_ = (char*)ldsA + ((j) & 3) * 16384; \
    __builtin_amdgcn_global_load_lds(GLOBAL_P(gA0 + (size_t)(j) * 64), LDS_P(b_ + ldst0), 16, 0, 0); \
    __builtin_amdgcn_global_load_lds(GLOBAL_P(gA1 + (size_t)(j) * 64), LDS_P(b_ + ldst1), 16, 0, 0); \
} while (0)
#define STAGE_B(j) do { \
    char* b_ = (char*)ldsB + ((j) & 3) * 16384; \
    __builtin_amdgcn_global_load_lds(GLOBAL_P(gB0 + (size_t)(j) * 64), LDS_P(b_ + ldst0), 16, 0, 0); \
    __builtin_amdgcn_global_load_lds(GLOBAL_P(gB1 + (size_t)(j) * 64), LDS_P(b_ + ldst1), 16, 0, 0); \
} while (0)
// DST is a 4-frag buffer; H selects which A-half's offsets to read.
#define LDAH(DST, H, SLOT) do { \
    const char* p_ = (const char*)ldsA + (SLOT) * 16384; \
    _Pragma("unroll") for (int i_ = 0; i_ < 4; ++i_) \
        DST[i_] = *(const short8*)(p_ + aoff[(H) * 4 + i_]); \
} while (0)
#define LDB4(DST, SLOT) do { \
    const char* p_ = (const char*)ldsB + (SLOT) * 16384; \
    _Pragma("unroll") for (int i_ = 0; i_ < 4; ++i_) \
        DST[i_] = *(const short8*)(p_ + boff[i_]); \
} while (0)
#define MFMAH(H, A4, B4) do { \
    SP1; \
    _Pragma("unroll") for (int mm_ = 0; mm_ < 4; ++mm_) \
        _Pragma("unroll") for (int nn_ = 0; nn_ < 4; ++nn_) \
            acc[(H) * 4 + mm_][nn_] = __builtin_amdgcn_mfma_f32_16x16x32_bf16( \
                A4[mm_], B4[nn_], acc[(H) * 4 + mm_][nn_], 0, 0, 0); \
    SP0; \
} while (0)

// Window j: SC = slot j&3 (cur), SN = slot (j+1)&3 (next), BC = cur B buf, BN_ = next B buf.
#define WINDOW(BC, BN_, SC, SN, JST, VM) do { \
    BARRIER(); \
    LDAH(aQ, 1, SC);            /* cur A h1 (consumed by MFMAH(1) this window) */ \
    STAGE_A(JST); \
    MFMAH(0, aP, BC); \
    LDAH(aP, 0, SN);            /* next A h0 (aP consumed by MFMAH(0) above) */ \
    LDB4(BN_, SN);              /* next B */ \
    STAGE_B(JST); \
    MFMAH(1, aQ, BC); \
    VM; \
} while (0)
#define WINDOW_NS(BC, BN_, SC, SN, VM) do { \
    BARRIER(); \
    LDAH(aQ, 1, SC); \
    MFMAH(0, aP, BC); \
    LDAH(aP, 0, SN); \
    LDB4(BN_, SN); \
    MFMAH(1, aQ, BC); \
    VM; \
} while (0)

    f32x4 acc[8][4] = {};
    short8 aP[4], aQ[4], bP[4], bQ[4];

    // ---- prologue: stage Kh0..Kh2 (slots 0,1,2); publish Kh0,Kh1; load cur h0+B ----
    STAGE_A(0); STAGE_B(0);
    STAGE_A(1); STAGE_B(1);
    STAGE_A(2); STAGE_B(2);
    WAITVM4();                 // 12 outstanding -> <=4: Kh0 AND Kh1 retired (all waves)
    BARRIER();                 // publish Kh0 (cur reads below) and Kh1 (window-0 next reads)
    LDAH(aP, 0, 0);            // cur A h0 (Kh0)
    LDB4(bP, 0);               // cur B    (Kh0)

    // ---- main loop: windows j = 0..251, 4 per iteration ----
    for (int kt = 0; kt < 63; ++kt) {
        const int j0 = 4 * kt;
        WINDOW(bP, bQ, 0, 1, j0 + 3, WAITVM4());   // j=j0   : VM4 drains Kh(j0+2)
        WINDOW(bQ, bP, 1, 2, j0 + 4, WAITVM4());   // j=j0+1
        WINDOW(bP, bQ, 2, 3, j0 + 5, WAITVM4());   // j=j0+2
        WINDOW(bQ, bP, 3, 0, j0 + 6, WAITVM4());   // j=j0+3
    }

    // ---- tail: j = 252 (stage Kh255), 253, 254, 255 ----
    WINDOW(bP, bQ, 0, 1, 255, WAITVM4());          // j=252: VM4 drains Kh254
    WINDOW_NS(bQ, bP, 1, 2, WAITVM0());            // j=253: VM0 drains Kh255
    WINDOW_NS(bP, bQ, 2, 3, (void)0);              // j=254: nothing outstanding
    BARRIER();                                     // j=255: MFMA only
    LDAH(aQ, 1, 3);
    MFMAH(0, aP, bQ);
    MFMAH(1, aQ, bQ);

    // ---- epilogue: C/D layout col = lane&15, row = (lane>>4)*4 + r ----
    const float s = *scale_p;
    const int colbase = colB0 + wc * 64 + rlane;
    const int rowbase = rowA0 + wr * 128 + kgrp * 4;
    #pragma unroll
    for (int n = 0; n < 4; ++n) {
        const float bv = bias[colbase + n * 16];
        #pragma unroll
        for (int mf = 0; mf < 8; ++mf) {
            #pragma unroll
            for (int r = 0; r < 4; ++r)
                out[(size_t)(rowbase + mf * 16 + r) * NF + colbase + n * 16] = acc[mf][n][r] * s + bv;
        }
    }
#undef STAGE_A
#undef STAGE_B
#undef LDAH
#undef LDB4
#undef MFMAH
#undef WINDOW
#undef WINDOW_NS
}

extern "C" void kernel_launch(void* const* d_in, const int* in_sizes, int n_in,
                              void* d_out, int out_size, void* d_ws, size_t ws_size,
                              hipStream_t stream) {
    const float* x      = (const float*)d_in[0];
    const int*   packed = (const int*)d_in[1];
    const int*   signs  = (const int*)d_in[2];
    const float* bias   = (const float*)d_in[3];
    const float* scale  = (const float*)d_in[4];
    const int*   minexp = (const int*)d_in[5];
    float* out = (float*)d_out;

    uint16_t* A = (uint16_t*)d_ws;                                       // 64 MiB
    uint16_t* W = (uint16_t*)((char*)d_ws + (size_t)N_TOK * KF * 2);     // 128 MiB

    quant_x<<<2048, 256, 0, stream>>>(x, scale, A);
    dequant_w<<<2048, 256, 0, stream>>>(packed, signs, minexp, W);
    gemm_bt<<<(N_TOK / BM) * (NF / BN), 512, 0, stream>>>(A, W, bias, scale, out);
}